// Round 11
// baseline (1672.715 us; speedup 1.0000x reference)
//
#include <hip/hip_runtime.h>
#include <math.h>

#define NR 8192
#define DDIM 128

static constexpr float LOG_AB2 = -13.0f;                  // -log2(8192)
static constexpr float OFF2    = -28.853900817779268f;    // -(1.0)*20*log2e constant shift
static constexpr float C8      = 0.11315255222658537f;    // (20/255)*log2e
static constexpr float DQK8    = 1.0f / 255.0f;
// RBF scale constants in log2 domain: -log2e/(2 s^2)
static constexpr float E1 = -0.7213475204444817f;
static constexpr float E2 = -0.18033688011112043f;
static constexpr float E3 = -0.045084220027780107f;
static constexpr float E4 = -0.011271055006945027f;
static constexpr float E5 = -0.0028177637517362567f;

typedef __attribute__((ext_vector_type(8))) _Float16 f16x8;
typedef __attribute__((ext_vector_type(4))) float    f32x4;

#if defined(__has_builtin)
#if __has_builtin(__builtin_amdgcn_exp2f)
#define EX2_IMPL(x) __builtin_amdgcn_exp2f(x)
#endif
#endif
#ifndef EX2_IMPL
extern "C" __device__ float __ocml_native_exp2_f32(float);
#define EX2_IMPL(x) __ocml_native_exp2_f32(x)
#endif
__device__ inline float ex2(float x) { return EX2_IMPL(x); }

typedef const unsigned int __attribute__((address_space(1)))* gas_ptr;
typedef unsigned int __attribute__((address_space(3)))*       las_ptr;
__device__ inline void gload16(const void* g, void* l) {
    __builtin_amdgcn_global_load_lds((gas_ptr)g, (las_ptr)l, 16, 0, 0);
}

__device__ inline unsigned short f2h(float f) {
    return __builtin_bit_cast(unsigned short, (_Float16)f);
}

// ---------------- f32 -> fp16 plane ----------------
__global__ __launch_bounds__(256) void convh_k(const float* __restrict__ X,
                                               unsigned short* __restrict__ H) {
    const int i = blockIdx.x * 1024 + threadIdx.x * 4;
    const float4 v = *reinterpret_cast<const float4*>(&X[i]);
    ushort4 h;
    h.x = f2h(v.x);
    h.y = f2h(v.y);
    h.z = f2h(v.z);
    h.w = f2h(v.w);
    *reinterpret_cast<ushort4*>(&H[i]) = h;
}

// ---------------- row squared-norms (exact f32) ----------------
__global__ __launch_bounds__(256) void rownorm_k(const float* __restrict__ X,
                                                 float* __restrict__ nrm) {
    const int lane = threadIdx.x & 63;
    const int w    = threadIdx.x >> 6;
    const int row  = blockIdx.x * 4 + w;
    const float2 v = *reinterpret_cast<const float2*>(&X[(size_t)row * DDIM + lane * 2]);
    float s = v.x * v.x + v.y * v.y;
#pragma unroll
    for (int off = 32; off; off >>= 1) s += __shfl_xor(s, off);
    if (lane == 0) nrm[row] = s;
}

// ---------------- fp16 MFMA GEMM + multi-scale RBF (single-stage full-K) ----------------
// As/Bs: [128 rows][128 halfs] = 256-B rows = 16 units of 16 B. Physical unit p at
// row r holds logical unit p^(r&15) (G21: linear gload dest + inverse-swizzled
// per-lane SOURCE + swizzled read). One stage + one barrier per block.
// MODE 0: full 64x64 grid (X vs Y), store uint8 K.
// MODE 1: triangular 2080 x 2 grid (sel: X or Y), sum only; double off-diag blocks.
template <int MODE>
__global__ __launch_bounds__(256) void gemm_mfma_k(const unsigned short* __restrict__ XF,
                                                   const unsigned short* __restrict__ YF,
                                                   const float* __restrict__ nxp,
                                                   const float* __restrict__ nyp,
                                                   unsigned char* __restrict__ K8,
                                                   double* __restrict__ sums) {
    int bm, bn;
    const unsigned short *A, *B;
    const float *na, *nb;
    if (MODE == 0) {
        bm = blockIdx.x; bn = blockIdx.y;
        A = XF; B = YF; na = nxp; nb = nyp;
    } else {
        const int lin = blockIdx.x;  // 0..2079 triangular (bm<=bn)
        int i = (int)((129.0f - sqrtf(16641.0f - 8.0f * (float)lin)) * 0.5f);
        while (i * 64 - i * (i - 1) / 2 > lin) --i;
        while ((i + 1) * 64 - (i + 1) * i / 2 <= lin) ++i;
        bm = i;
        bn = i + (lin - (i * 64 - i * (i - 1) / 2));
        const int sel = blockIdx.y;
        A = B = sel ? YF : XF;
        na = nb = sel ? nyp : nxp;
    }
    __shared__ unsigned short As[128 * 128];   // 32 KB
    __shared__ unsigned short Bs[128 * 128];   // 32 KB

    const int t    = threadIdx.x;
    const int lane = t & 63;
    const int w    = t >> 6;
    const int wr   = w >> 1, wc = w & 1;      // 2x2 wave grid, 64x64 sub-tile each
    const int l15  = lane & 15, lg = lane >> 4;

    // staging lane constants: each gload call covers 4 rows x 16 units
    const int r4 = lane >> 4;                 // row-within-call 0..3
    const int p  = lane & 15;                 // physical unit

    f32x4 acc[4][4];
#pragma unroll
    for (int mi = 0; mi < 4; ++mi)
#pragma unroll
        for (int ni = 0; ni < 4; ++ni) acc[mi][ni] = (f32x4){0.f, 0.f, 0.f, 0.f};

    // ---- single staging phase: whole 128x128 A and B tiles ----
#pragma unroll
    for (int c = 0; c < 8; ++c) {
        const int rloc = w * 32 + c * 4 + r4;            // 0..127
        const int u    = p ^ (rloc & 15);                // logical unit (16-B granules)
        gload16(A + (size_t)(bm * 128 + rloc) * DDIM + u * 8, &As[(w * 32 + c * 4) * 128]);
        gload16(B + (size_t)(bn * 128 + rloc) * DDIM + u * 8, &Bs[(w * 32 + c * 4) * 128]);
    }
    __syncthreads();

    // ---- 64 MFMAs, no further barriers ----
#pragma unroll
    for (int ks = 0; ks < 4; ++ks) {
        f16x8 bf[4];
#pragma unroll
        for (int ni = 0; ni < 4; ++ni) {
            const int R = wc * 64 + ni * 16 + l15;       // R & 15 == l15
            bf[ni] = *reinterpret_cast<const f16x8*>(&Bs[R * 128 + ((ks * 4 + lg) ^ l15) * 8]);
        }
#pragma unroll
        for (int mi = 0; mi < 4; ++mi) {
            const int R = wr * 64 + mi * 16 + l15;
            const f16x8 af = *reinterpret_cast<const f16x8*>(&As[R * 128 + ((ks * 4 + lg) ^ l15) * 8]);
#pragma unroll
            for (int ni = 0; ni < 4; ++ni)
                acc[mi][ni] = __builtin_amdgcn_mfma_f32_16x16x32_f16(af, bf[ni], acc[mi][ni], 0, 0, 0);
        }
    }

    // epilogue; C/D layout: col = lane&15, row = (lane>>4)*4 + j  [HW-verified]
    const int mBase = bm * 128 + wr * 64;
    const int nBase = bn * 128 + wc * 64;
    float nbv[4];
#pragma unroll
    for (int ni = 0; ni < 4; ++ni) nbv[ni] = nb[nBase + ni * 16 + l15];

    if (MODE == 0) {
#pragma unroll
        for (int mi = 0; mi < 4; ++mi) {
#pragma unroll
            for (int j = 0; j < 4; ++j) {
                const int m = mBase + mi * 16 + lg * 4 + j;
                const float nav = na[m];
                unsigned char* krow = &K8[(size_t)m * NR + nBase + l15];
#pragma unroll
                for (int ni = 0; ni < 4; ++ni) {
                    float d2 = fmaf(-2.f, acc[mi][ni][j], nav + nbv[ni]);
                    d2 = fmaxf(d2, 0.f);
                    const float kv = 0.2f * (ex2(d2 * E1) + ex2(d2 * E2) + ex2(d2 * E3) +
                                             ex2(d2 * E4) + ex2(d2 * E5));
                    krow[ni * 16] = (unsigned char)__float2uint_rn(kv * 255.f);
                }
            }
        }
    } else {
        double lsum = 0.0;
#pragma unroll
        for (int mi = 0; mi < 4; ++mi) {
#pragma unroll
            for (int j = 0; j < 4; ++j) {
                const int m = mBase + mi * 16 + lg * 4 + j;
                const float nav = na[m];
                float rs = 0.f;
#pragma unroll
                for (int ni = 0; ni < 4; ++ni) {
                    float d2 = fmaf(-2.f, acc[mi][ni][j], nav + nbv[ni]);
                    d2 = fmaxf(d2, 0.f);
                    rs += 0.2f * (ex2(d2 * E1) + ex2(d2 * E2) + ex2(d2 * E3) +
                                  ex2(d2 * E4) + ex2(d2 * E5));
                }
                lsum += (double)rs;
            }
        }
        if (bn > bm) lsum *= 2.0;
#pragma unroll
        for (int o = 32; o; o >>= 1) lsum += __shfl_xor(lsum, o);
        if (lane == 0) atomicAdd(&sums[1 + blockIdx.y], lsum);
    }
}

// log_v initial state: exact log_v=0 -> stored = OFF2
__global__ __launch_bounds__(256) void init_lv_k(float* __restrict__ log_v) {
    log_v[blockIdx.x * 256 + threadIdx.x] = OFF2;
}

// ---------------- Sinkhorn row pass: 16 rows/block ----------------
__global__ __launch_bounds__(256) void sink_row_k(const unsigned char* __restrict__ K8,
                                                  const float* __restrict__ log_v,
                                                  float* __restrict__ log_u) {
    __shared__ float red[4][16];
    const int t  = threadIdx.x;
    const int r0 = blockIdx.x * 16;
    const float4* Lv4 = reinterpret_cast<const float4*>(log_v);
    float s[16];
#pragma unroll
    for (int r = 0; r < 16; ++r) s[r] = 0.f;
#pragma unroll
    for (int pp = 0; pp < 2; ++pp) {
        const int g = t + pp * 256;  // uint4 group: cols 16g..16g+15
        const float4 l0 = Lv4[4 * g + 0];
        const float4 l1 = Lv4[4 * g + 1];
        const float4 l2 = Lv4[4 * g + 2];
        const float4 l3 = Lv4[4 * g + 3];
        const float lvv[16] = {l0.x, l0.y, l0.z, l0.w, l1.x, l1.y, l1.z, l1.w,
                               l2.x, l2.y, l2.z, l2.w, l3.x, l3.y, l3.z, l3.w};
        const uint4* col = reinterpret_cast<const uint4*>(K8 + (size_t)r0 * NR) + g;
#pragma unroll
        for (int r = 0; r < 16; ++r) {
            const uint4 wq = col[(size_t)r * 512];
            const unsigned wd[4] = {wq.x, wq.y, wq.z, wq.w};
#pragma unroll
            for (int d = 0; d < 4; ++d) {
                const unsigned a = wd[d];
                s[r] += ex2(fmaf((float)(a & 255u),          C8, lvv[4 * d + 0]))
                      + ex2(fmaf((float)((a >> 8) & 255u),   C8, lvv[4 * d + 1]))
                      + ex2(fmaf((float)((a >> 16) & 255u),  C8, lvv[4 * d + 2]))
                      + ex2(fmaf((float)(a >> 24),           C8, lvv[4 * d + 3]));
            }
        }
    }
    const int lane = t & 63, wv = t >> 6;
#pragma unroll
    for (int r = 0; r < 16; ++r) {
        float v = s[r];
#pragma unroll
        for (int o = 32; o; o >>= 1) v += __shfl_xor(v, o);
        if (lane == 0) red[wv][r] = v;
    }
    __syncthreads();
    if (t < 16) {
        const float stot = (red[0][t] + red[1][t]) + (red[2][t] + red[3][t]);
        log_u[r0 + t] = LOG_AB2 - __log2f(stot) + OFF2;
    }
}

// ---------------- Sinkhorn column pass: partial sums over 32-row chunks ----------------
__global__ __launch_bounds__(256) void sink_colp_k(const unsigned char* __restrict__ K8,
                                                   const float* __restrict__ log_u,
                                                   float* __restrict__ ps) {
    const int t   = threadIdx.x;
    const int cg4 = blockIdx.x * 256 + t;
    const int rc  = blockIdx.y;
    const uint4* base = reinterpret_cast<const uint4*>(K8) + (size_t)rc * 32 * 512 + cg4;
    const float* lu = log_u + rc * 32;
    float s16[16];
#pragma unroll
    for (int e = 0; e < 16; ++e) s16[e] = 0.f;
#pragma unroll 4
    for (int r = 0; r < 32; ++r) {
        const uint4 wq = base[(size_t)r * 512];
        const float lur = lu[r];
        const unsigned wd[4] = {wq.x, wq.y, wq.z, wq.w};
#pragma unroll
        for (int d = 0; d < 4; ++d) {
            const unsigned a = wd[d];
            s16[4 * d + 0] += ex2(fmaf((float)(a & 255u),         C8, lur));
            s16[4 * d + 1] += ex2(fmaf((float)((a >> 8) & 255u),  C8, lur));
            s16[4 * d + 2] += ex2(fmaf((float)((a >> 16) & 255u), C8, lur));
            s16[4 * d + 3] += ex2(fmaf((float)(a >> 24),          C8, lur));
        }
    }
    float4* pv = reinterpret_cast<float4*>(ps + (size_t)rc * NR + cg4 * 16);
#pragma unroll
    for (int d = 0; d < 4; ++d)
        pv[d] = {s16[4 * d + 0], s16[4 * d + 1], s16[4 * d + 2], s16[4 * d + 3]};
}

__global__ __launch_bounds__(256) void sink_combine_k(const float* __restrict__ ps,
                                                      float* __restrict__ log_v) {
    __shared__ float red[4][64];
    const int lane = threadIdx.x & 63;
    const int grp  = threadIdx.x >> 6;
    const int col  = blockIdx.x * 64 + lane;
    float s = 0.f;
#pragma unroll 8
    for (int c = grp * 64; c < grp * 64 + 64; ++c) s += ps[(size_t)c * NR + col];
    red[grp][lane] = s;
    __syncthreads();
    if (grp == 0) {
        const float stot = (red[0][lane] + red[1][lane]) + (red[2][lane] + red[3][lane]);
        log_v[col] = LOG_AB2 - __log2f(stot) + OFF2;
    }
}

// ---------------- final sum(Gamma * Kxy); scaled by DQK8 in finalize ----------------
__global__ __launch_bounds__(256) void gamma_sum_k(const unsigned char* __restrict__ K8,
                                                   const float* __restrict__ log_u,
                                                   const float* __restrict__ log_v,
                                                   double* __restrict__ S) {
    const int t   = threadIdx.x;
    const int cg4 = blockIdx.x * 256 + t;
    const int rc  = blockIdx.y;
    float lvp[16];
#pragma unroll
    for (int e = 0; e < 16; ++e) lvp[e] = log_v[cg4 * 16 + e] - OFF2;
    const uint4* base = reinterpret_cast<const uint4*>(K8) + (size_t)rc * 32 * 512 + cg4;
    const float* lu = log_u + rc * 32;
    double acc = 0.0;
#pragma unroll 4
    for (int r = 0; r < 32; ++r) {
        const uint4 w = base[(size_t)r * 512];
        const float lur = lu[r];
        const unsigned wd[4] = {w.x, w.y, w.z, w.w};
        float rs = 0.f;
#pragma unroll
        for (int d = 0; d < 4; ++d) {
            const unsigned a = wd[d];
            const float q0 = (float)(a & 255u);
            const float q1 = (float)((a >> 8) & 255u);
            const float q2 = (float)((a >> 16) & 255u);
            const float q3 = (float)(a >> 24);
            rs = fmaf(ex2(fmaf(q0, C8, lur + lvp[4 * d + 0])), q0, rs);
            rs = fmaf(ex2(fmaf(q1, C8, lur + lvp[4 * d + 1])), q1, rs);
            rs = fmaf(ex2(fmaf(q2, C8, lur + lvp[4 * d + 2])), q2, rs);
            rs = fmaf(ex2(fmaf(q3, C8, lur + lvp[4 * d + 3])), q3, rs);
        }
        acc += (double)rs;
    }
#pragma unroll
    for (int o = 32; o; o >>= 1) acc += __shfl_xor(acc, o);
    if ((t & 63) == 0) atomicAdd(S, acc);
}

__global__ void finalize_k(const double* __restrict__ scal, float* __restrict__ out) {
    const double inv = 1.0 / (8192.0 * 8192.0);
    out[0] = (float)(scal[1] * inv + scal[2] * inv - 2.0 * (double)DQK8 * scal[3]);
}

extern "C" void kernel_launch(void* const* d_in, const int* in_sizes, int n_in,
                              void* d_out, int out_size, void* d_ws, size_t ws_size,
                              hipStream_t stream) {
    const float* X = (const float*)d_in[0];
    const float* Y = (const float*)d_in[1];

    // ---- workspace layout ----
    char* ws = (char*)d_ws;
    unsigned char* K8 = (unsigned char*)ws;               // 67108864 B
    float* nx    = (float*)(ws + 67108864);               // 32 KB each
    float* ny    = nx + NR;
    float* log_u = ny + NR;
    float* log_v = log_u + NR;
    char*  scal  = (char*)(log_v + NR);                   // 512 B
    double* scal_d = (double*)scal;                       // [1]=kxx, [2]=kyy, [3]=S
    float* ps = (float*)(scal + 512);                     // 8 MB
    unsigned short* XF = (unsigned short*)(ws + 75629056);  // 2 MB each
    unsigned short* YF = XF + NR * DDIM;
    const size_t needed = 75629056 + 2 * (size_t)NR * DDIM * 2;
    if (ws_size < needed) return;  // clean absmax failure instead of a GPU fault

    (void)hipMemsetAsync(scal, 0, 512, stream);  // sums = 0

    convh_k<<<NR * DDIM / 1024, 256, 0, stream>>>(X, XF);
    convh_k<<<NR * DDIM / 1024, 256, 0, stream>>>(Y, YF);
    rownorm_k<<<NR / 4, 256, 0, stream>>>(X, nx);
    rownorm_k<<<NR / 4, 256, 0, stream>>>(Y, ny);

    gemm_mfma_k<0><<<dim3(64, 64), 256, 0, stream>>>(XF, YF, nx, ny, K8, scal_d);
    gemm_mfma_k<1><<<dim3(2080, 2), 256, 0, stream>>>(XF, YF, nx, ny, nullptr, scal_d);

    init_lv_k<<<NR / 256, 256, 0, stream>>>(log_v);

    for (int it = 0; it < 30; ++it) {
        sink_row_k<<<NR / 16, 256, 0, stream>>>(K8, log_v, log_u);
        sink_colp_k<<<dim3(2, 256), 256, 0, stream>>>(K8, log_u, ps);
        sink_combine_k<<<128, 256, 0, stream>>>(ps, log_v);
    }

    gamma_sum_k<<<dim3(2, 256), 256, 0, stream>>>(K8, log_u, log_v, scal_d + 3);
    finalize_k<<<1, 1, 0, stream>>>(scal_d, (float*)d_out);
}

// Round 12
// 1424.176 us; speedup vs baseline: 1.1745x; 1.1745x over previous
//
#include <hip/hip_runtime.h>
#include <math.h>

#define NR 8192
#define DDIM 128

static constexpr float LOG_AB2 = -13.0f;                  // -log2(8192)
static constexpr float OFF2    = -28.853900817779268f;    // -(1.0)*20*log2e constant shift
static constexpr float C8      = 0.11315255222658537f;    // (20/255)*log2e
static constexpr float DQK8    = 1.0f / 255.0f;
// RBF scale constants in log2 domain: -log2e/(2 s^2)
static constexpr float E1 = -0.7213475204444817f;
static constexpr float E2 = -0.18033688011112043f;
static constexpr float E3 = -0.045084220027780107f;
static constexpr float E4 = -0.011271055006945027f;
static constexpr float E5 = -0.0028177637517362567f;

typedef __attribute__((ext_vector_type(8))) _Float16 f16x8;
typedef __attribute__((ext_vector_type(4))) float    f32x4;

#if defined(__has_builtin)
#if __has_builtin(__builtin_amdgcn_exp2f)
#define EX2_IMPL(x) __builtin_amdgcn_exp2f(x)
#endif
#endif
#ifndef EX2_IMPL
extern "C" __device__ float __ocml_native_exp2_f32(float);
#define EX2_IMPL(x) __ocml_native_exp2_f32(x)
#endif
__device__ inline float ex2(float x) { return EX2_IMPL(x); }

typedef const unsigned int __attribute__((address_space(1)))* gas_ptr;
typedef unsigned int __attribute__((address_space(3)))*       las_ptr;
__device__ inline void gload16(const void* g, void* l) {
    __builtin_amdgcn_global_load_lds((gas_ptr)g, (las_ptr)l, 16, 0, 0);
}

__device__ inline unsigned short f2h(float f) {
    return __builtin_bit_cast(unsigned short, (_Float16)f);
}

// ---------------- f32 -> fp16 plane ----------------
__global__ __launch_bounds__(256) void convh_k(const float* __restrict__ X,
                                               unsigned short* __restrict__ H) {
    const int i = blockIdx.x * 1024 + threadIdx.x * 4;
    const float4 v = *reinterpret_cast<const float4*>(&X[i]);
    ushort4 h;
    h.x = f2h(v.x);
    h.y = f2h(v.y);
    h.z = f2h(v.z);
    h.w = f2h(v.w);
    *reinterpret_cast<ushort4*>(&H[i]) = h;
}

// ---------------- row squared-norms (exact f32) ----------------
__global__ __launch_bounds__(256) void rownorm_k(const float* __restrict__ X,
                                                 float* __restrict__ nrm) {
    const int lane = threadIdx.x & 63;
    const int w    = threadIdx.x >> 6;
    const int row  = blockIdx.x * 4 + w;
    const float2 v = *reinterpret_cast<const float2*>(&X[(size_t)row * DDIM + lane * 2]);
    float s = v.x * v.x + v.y * v.y;
#pragma unroll
    for (int off = 32; off; off >>= 1) s += __shfl_xor(s, off);
    if (lane == 0) nrm[row] = s;
}

// ---------------- fp16 MFMA GEMM + multi-scale RBF ----------------
// R10 staging: combined LDS tile, 128-B rows = 8 units of 16 B; units 0-3 = A row,
// 4-7 = B row; physical unit p at row r holds logical unit p^(r&7) (G21 pattern).
// MFMA operands SWAPPED: acc[mi][ni] holds D with col=lane&15 -> m, row=lg*4+j -> n,
// so each lane owns 4 consecutive n (columns) -> uchar4 stores.
// MODE 0: full 64x64 grid (X vs Y), store uint8 K.
// MODE 1: triangular 2080 x 2 grid (sel: X or Y), per-block partial to bsum[] (NO atomics).
template <int MODE>
__global__ __launch_bounds__(256) void gemm_mfma_k(const unsigned short* __restrict__ XF,
                                                   const unsigned short* __restrict__ YF,
                                                   const float* __restrict__ nxp,
                                                   const float* __restrict__ nyp,
                                                   unsigned char* __restrict__ K8,
                                                   double* __restrict__ bsum) {
    int bm, bn;
    const unsigned short *A, *B;
    const float *na, *nb;
    if (MODE == 0) {
        bm = blockIdx.x; bn = blockIdx.y;
        A = XF; B = YF; na = nxp; nb = nyp;
    } else {
        const int lin = blockIdx.x;  // 0..2079 triangular (bm<=bn)
        int i = (int)((129.0f - sqrtf(16641.0f - 8.0f * (float)lin)) * 0.5f);
        while (i * 64 - i * (i - 1) / 2 > lin) --i;
        while ((i + 1) * 64 - (i + 1) * i / 2 <= lin) ++i;
        bm = i;
        bn = i + (lin - (i * 64 - i * (i - 1) / 2));
        const int sel = blockIdx.y;
        A = B = sel ? YF : XF;
        na = nb = sel ? nyp : nxp;
    }
    __shared__ unsigned short Tile[128 * 64];   // 16 KB
    __shared__ double redd[4];

    const int t    = threadIdx.x;
    const int lane = t & 63;
    const int w    = t >> 6;
    const int wr   = w >> 1, wc = w & 1;      // 2x2 wave grid, 64x64 sub-tile each
    const int l15  = lane & 15, lg = lane >> 4;

    // staging lane constants: 8 rows x 8 units per 1024B call
    const int lr = lane >> 3;                 // row-within-call 0..7
    const int u  = (lane & 7) ^ lr;           // logical unit
    const int ss = u & 3;                     // k-seg within matrix

    f32x4 acc[4][4];
#pragma unroll
    for (int mi = 0; mi < 4; ++mi)
#pragma unroll
        for (int ni = 0; ni < 4; ++ni) acc[mi][ni] = (f32x4){0.f, 0.f, 0.f, 0.f};

    // per-lane global source base: A-tile rows for u<4, B-tile rows for u>=4
    const unsigned short* src = (u < 4)
        ? A + (size_t)(bm * 128 + lr) * DDIM + ss * 8
        : B + (size_t)(bn * 128 + lr) * DDIM + ss * 8;

    for (int kc = 0; kc < 4; ++kc) {
        if (kc) __syncthreads();
        const int ko = kc * 32;
#pragma unroll
        for (int c = 0; c < 4; ++c) {
            const int row0 = w * 32 + c * 8;   // this call stages rows [row0, row0+8)
            gload16(src + (size_t)row0 * DDIM + ko, &Tile[row0 * 64]);
        }
        __syncthreads();

        f16x8 bf[4];
#pragma unroll
        for (int ni = 0; ni < 4; ++ni) {
            const int R = wc * 64 + ni * 16 + l15;
            bf[ni] = *reinterpret_cast<const f16x8*>(&Tile[R * 64 + ((4 + lg) ^ (R & 7)) * 8]);
        }
#pragma unroll
        for (int mi = 0; mi < 4; ++mi) {
            const int R = wr * 64 + mi * 16 + l15;
            const f16x8 af = *reinterpret_cast<const f16x8*>(&Tile[R * 64 + (lg ^ (R & 7)) * 8]);
#pragma unroll
            for (int ni = 0; ni < 4; ++ni)   // SWAPPED operand order: D[n, m]
                acc[mi][ni] = __builtin_amdgcn_mfma_f32_16x16x32_f16(bf[ni], af, acc[mi][ni], 0, 0, 0);
        }
    }

    // epilogue with swapped layout: m = mBase + mi*16 + l15 ; n = nBase + ni*16 + lg*4 + j
    const int mBase = bm * 128 + wr * 64;
    const int nBase = bn * 128 + wc * 64;
    float nav[4];
#pragma unroll
    for (int mi = 0; mi < 4; ++mi) nav[mi] = na[mBase + mi * 16 + l15];

    if (MODE == 0) {
#pragma unroll
        for (int ni = 0; ni < 4; ++ni) {
            const float4 nb4 = *reinterpret_cast<const float4*>(&nb[nBase + ni * 16 + lg * 4]);
            const float nbj[4] = {nb4.x, nb4.y, nb4.z, nb4.w};
#pragma unroll
            for (int mi = 0; mi < 4; ++mi) {
                const int m = mBase + mi * 16 + l15;
                unsigned o = 0;
#pragma unroll
                for (int j = 0; j < 4; ++j) {
                    float d2 = fmaf(-2.f, acc[mi][ni][j], nav[mi] + nbj[j]);
                    d2 = fmaxf(d2, 0.f);
                    const float kv = 0.2f * (ex2(d2 * E1) + ex2(d2 * E2) + ex2(d2 * E3) +
                                             ex2(d2 * E4) + ex2(d2 * E5));
                    o |= (unsigned)(unsigned char)__float2uint_rn(kv * 255.f) << (8 * j);
                }
                *reinterpret_cast<unsigned*>(&K8[(size_t)m * NR + nBase + ni * 16 + lg * 4]) = o;
            }
        }
    } else {
        double lsum = 0.0;
#pragma unroll
        for (int ni = 0; ni < 4; ++ni) {
            const float4 nb4 = *reinterpret_cast<const float4*>(&nb[nBase + ni * 16 + lg * 4]);
            const float nbj[4] = {nb4.x, nb4.y, nb4.z, nb4.w};
#pragma unroll
            for (int mi = 0; mi < 4; ++mi) {
                float rs = 0.f;
#pragma unroll
                for (int j = 0; j < 4; ++j) {
                    float d2 = fmaf(-2.f, acc[mi][ni][j], nav[mi] + nbj[j]);
                    d2 = fmaxf(d2, 0.f);
                    rs += 0.2f * (ex2(d2 * E1) + ex2(d2 * E2) + ex2(d2 * E3) +
                                  ex2(d2 * E4) + ex2(d2 * E5));
                }
                lsum += (double)rs;
            }
        }
        if (bn > bm) lsum *= 2.0;
#pragma unroll
        for (int o = 32; o; o >>= 1) lsum += __shfl_xor(lsum, o);
        if (lane == 0) redd[w] = lsum;
        __syncthreads();
        if (t == 0)
            bsum[(size_t)blockIdx.y * 2080 + blockIdx.x] =
                (redd[0] + redd[1]) + (redd[2] + redd[3]);
    }
}

// reduce per-block partials -> scal_d[1], scal_d[2]
__global__ __launch_bounds__(256) void reduce_sums_k(const double* __restrict__ bsum,
                                                     double* __restrict__ scal_d) {
    __shared__ double red[8];
    const int t = threadIdx.x, lane = t & 63, w = t >> 6;
#pragma unroll
    for (int half = 0; half < 2; ++half) {
        double s = 0.0;
        for (int i = t; i < 2080; i += 256) s += bsum[half * 2080 + i];
#pragma unroll
        for (int o = 32; o; o >>= 1) s += __shfl_xor(s, o);
        if (lane == 0) red[w] = s;
        __syncthreads();
        if (t == 0) scal_d[1 + half] = (red[0] + red[1]) + (red[2] + red[3]);
        __syncthreads();
    }
}

// log_v initial state: exact log_v=0 -> stored = OFF2
__global__ __launch_bounds__(256) void init_lv_k(float* __restrict__ log_v) {
    log_v[blockIdx.x * 256 + threadIdx.x] = OFF2;
}

// ---------------- Sinkhorn row pass: 8 rows/block (proven R10 path) ----------------
__global__ __launch_bounds__(256) void sink_row_k(const unsigned char* __restrict__ K8,
                                                  const float* __restrict__ log_v,
                                                  float* __restrict__ log_u) {
    __shared__ float red[4][8];
    const int t  = threadIdx.x;
    const int r0 = blockIdx.x * 8;
    const float4* Lv4 = reinterpret_cast<const float4*>(log_v);
    float s[8];
#pragma unroll
    for (int r = 0; r < 8; ++r) s[r] = 0.f;
#pragma unroll
    for (int p = 0; p < 2; ++p) {
        const int g = t + p * 256;  // uint4 group: cols 16g..16g+15
        const float4 l0 = Lv4[4 * g + 0];
        const float4 l1 = Lv4[4 * g + 1];
        const float4 l2 = Lv4[4 * g + 2];
        const float4 l3 = Lv4[4 * g + 3];
        const float lvv[16] = {l0.x, l0.y, l0.z, l0.w, l1.x, l1.y, l1.z, l1.w,
                               l2.x, l2.y, l2.z, l2.w, l3.x, l3.y, l3.z, l3.w};
        const uint4* col = reinterpret_cast<const uint4*>(K8 + (size_t)r0 * NR) + g;
#pragma unroll
        for (int r = 0; r < 8; ++r) {
            const uint4 wq = col[(size_t)r * 512];
            const unsigned wd[4] = {wq.x, wq.y, wq.z, wq.w};
#pragma unroll
            for (int d = 0; d < 4; ++d) {
                const unsigned a = wd[d];
                s[r] += ex2(fmaf((float)(a & 255u),          C8, lvv[4 * d + 0]))
                      + ex2(fmaf((float)((a >> 8) & 255u),   C8, lvv[4 * d + 1]))
                      + ex2(fmaf((float)((a >> 16) & 255u),  C8, lvv[4 * d + 2]))
                      + ex2(fmaf((float)(a >> 24),           C8, lvv[4 * d + 3]));
            }
        }
    }
    const int lane = t & 63, wv = t >> 6;
#pragma unroll
    for (int r = 0; r < 8; ++r) {
        float v = s[r];
#pragma unroll
        for (int o = 32; o; o >>= 1) v += __shfl_xor(v, o);
        if (lane == 0) red[wv][r] = v;
    }
    __syncthreads();
    if (t < 8) {
        const float stot = (red[0][t] + red[1][t]) + (red[2][t] + red[3][t]);
        log_u[r0 + t] = LOG_AB2 - __log2f(stot) + OFF2;
    }
}

// ---------------- Sinkhorn column pass: partial sums over 32-row chunks ----------------
__global__ __launch_bounds__(256) void sink_colp_k(const unsigned char* __restrict__ K8,
                                                   const float* __restrict__ log_u,
                                                   float* __restrict__ ps) {
    const int t   = threadIdx.x;
    const int cg4 = blockIdx.x * 256 + t;
    const int rc  = blockIdx.y;
    const uint4* base = reinterpret_cast<const uint4*>(K8) + (size_t)rc * 32 * 512 + cg4;
    const float* lu = log_u + rc * 32;
    float s16[16];
#pragma unroll
    for (int e = 0; e < 16; ++e) s16[e] = 0.f;
#pragma unroll 4
    for (int r = 0; r < 32; ++r) {
        const uint4 wq = base[(size_t)r * 512];
        const float lur = lu[r];
        const unsigned wd[4] = {wq.x, wq.y, wq.z, wq.w};
#pragma unroll
        for (int d = 0; d < 4; ++d) {
            const unsigned a = wd[d];
            s16[4 * d + 0] += ex2(fmaf((float)(a & 255u),         C8, lur));
            s16[4 * d + 1] += ex2(fmaf((float)((a >> 8) & 255u),  C8, lur));
            s16[4 * d + 2] += ex2(fmaf((float)((a >> 16) & 255u), C8, lur));
            s16[4 * d + 3] += ex2(fmaf((float)(a >> 24),          C8, lur));
        }
    }
    float4* pv = reinterpret_cast<float4*>(ps + (size_t)rc * NR + cg4 * 16);
#pragma unroll
    for (int d = 0; d < 4; ++d)
        pv[d] = {s16[4 * d + 0], s16[4 * d + 1], s16[4 * d + 2], s16[4 * d + 3]};
}

__global__ __launch_bounds__(256) void sink_combine_k(const float* __restrict__ ps,
                                                      float* __restrict__ log_v) {
    __shared__ float red[4][64];
    const int lane = threadIdx.x & 63;
    const int grp  = threadIdx.x >> 6;
    const int col  = blockIdx.x * 64 + lane;
    float s = 0.f;
#pragma unroll 8
    for (int c = grp * 64; c < grp * 64 + 64; ++c) s += ps[(size_t)c * NR + col];
    red[grp][lane] = s;
    __syncthreads();
    if (grp == 0) {
        const float stot = (red[0][lane] + red[1][lane]) + (red[2][lane] + red[3][lane]);
        log_v[col] = LOG_AB2 - __log2f(stot) + OFF2;
    }
}

// ---------------- final sum(Gamma * Kxy); scaled by DQK8 in finalize ----------------
__global__ __launch_bounds__(256) void gamma_sum_k(const unsigned char* __restrict__ K8,
                                                   const float* __restrict__ log_u,
                                                   const float* __restrict__ log_v,
                                                   double* __restrict__ S) {
    const int t   = threadIdx.x;
    const int cg4 = blockIdx.x * 256 + t;
    const int rc  = blockIdx.y;
    float lvp[16];
#pragma unroll
    for (int e = 0; e < 16; ++e) lvp[e] = log_v[cg4 * 16 + e] - OFF2;
    const uint4* base = reinterpret_cast<const uint4*>(K8) + (size_t)rc * 32 * 512 + cg4;
    const float* lu = log_u + rc * 32;
    double acc = 0.0;
#pragma unroll 4
    for (int r = 0; r < 32; ++r) {
        const uint4 w = base[(size_t)r * 512];
        const float lur = lu[r];
        const unsigned wd[4] = {w.x, w.y, w.z, w.w};
        float rs = 0.f;
#pragma unroll
        for (int d = 0; d < 4; ++d) {
            const unsigned a = wd[d];
            const float q0 = (float)(a & 255u);
            const float q1 = (float)((a >> 8) & 255u);
            const float q2 = (float)((a >> 16) & 255u);
            const float q3 = (float)(a >> 24);
            rs = fmaf(ex2(fmaf(q0, C8, lur + lvp[4 * d + 0])), q0, rs);
            rs = fmaf(ex2(fmaf(q1, C8, lur + lvp[4 * d + 1])), q1, rs);
            rs = fmaf(ex2(fmaf(q2, C8, lur + lvp[4 * d + 2])), q2, rs);
            rs = fmaf(ex2(fmaf(q3, C8, lur + lvp[4 * d + 3])), q3, rs);
        }
        acc += (double)rs;
    }
#pragma unroll
    for (int o = 32; o; o >>= 1) acc += __shfl_xor(acc, o);
    if ((t & 63) == 0) atomicAdd(S, acc);
}

__global__ void finalize_k(const double* __restrict__ scal, float* __restrict__ out) {
    const double inv = 1.0 / (8192.0 * 8192.0);
    out[0] = (float)(scal[1] * inv + scal[2] * inv - 2.0 * (double)DQK8 * scal[3]);
}

extern "C" void kernel_launch(void* const* d_in, const int* in_sizes, int n_in,
                              void* d_out, int out_size, void* d_ws, size_t ws_size,
                              hipStream_t stream) {
    const float* X = (const float*)d_in[0];
    const float* Y = (const float*)d_in[1];

    // ---- workspace layout ----
    char* ws = (char*)d_ws;
    unsigned char* K8 = (unsigned char*)ws;               // 67108864 B
    float* nx    = (float*)(ws + 67108864);               // 32 KB each
    float* ny    = nx + NR;
    float* log_u = ny + NR;
    float* log_v = log_u + NR;
    char*  scal  = (char*)(log_v + NR);                   // 512 B
    double* scal_d = (double*)scal;                       // [1]=kxx, [2]=kyy, [3]=S
    float* ps = (float*)(scal + 512);                     // 8 MB (bsum aliases front)
    double* bsum = (double*)ps;                           // 4160 doubles (pre-sink only)
    unsigned short* XF = (unsigned short*)(ws + 75629056);  // 2 MB each
    unsigned short* YF = XF + NR * DDIM;
    const size_t needed = 75629056 + 2 * (size_t)NR * DDIM * 2;
    if (ws_size < needed) return;  // clean absmax failure instead of a GPU fault

    (void)hipMemsetAsync(scal, 0, 512, stream);  // sums = 0

    convh_k<<<NR * DDIM / 1024, 256, 0, stream>>>(X, XF);
    convh_k<<<NR * DDIM / 1024, 256, 0, stream>>>(Y, YF);
    rownorm_k<<<NR / 4, 256, 0, stream>>>(X, nx);
    rownorm_k<<<NR / 4, 256, 0, stream>>>(Y, ny);

    gemm_mfma_k<0><<<dim3(64, 64), 256, 0, stream>>>(XF, YF, nx, ny, K8, nullptr);
    gemm_mfma_k<1><<<dim3(2080, 2), 256, 0, stream>>>(XF, YF, nx, ny, nullptr, bsum);
    reduce_sums_k<<<1, 256, 0, stream>>>(bsum, scal_d);

    init_lv_k<<<NR / 256, 256, 0, stream>>>(log_v);

    for (int it = 0; it < 30; ++it) {
        sink_row_k<<<NR / 8, 256, 0, stream>>>(K8, log_v, log_u);
        sink_colp_k<<<dim3(2, 256), 256, 0, stream>>>(K8, log_u, ps);
        sink_combine_k<<<128, 256, 0, stream>>>(ps, log_v);
    }

    gamma_sum_k<<<dim3(2, 256), 256, 0, stream>>>(K8, log_u, log_v, scal_d + 3);
    finalize_k<<<1, 1, 0, stream>>>(scal_d, (float*)d_out);
}